// Round 1
// baseline (149.917 us; speedup 1.0000x reference)
//
#include <hip/hip_runtime.h>
#include <hip/hip_bf16.h>
#include <math.h>

// Problem constants (from reference setup_inputs)
constexpr int B = 4, S = 10, N = 2048, D = 128;
constexpr int QPB = 256;            // queries per block (1 per thread)
constexpr int CHUNKS = N / QPB;     // 8 row-chunks per (b,s,dir)

// ws layout (floats): [0]=chamfer min-dist grand sum, [1]=kl term sum, [2]=temporal sum

__device__ __forceinline__ void wave_reduce_atomic(float v, float* dst) {
    // wave64 shuffle reduction, then one atomic per wave
    #pragma unroll
    for (int off = 32; off > 0; off >>= 1)
        v += __shfl_down(v, off, 64);
    if ((threadIdx.x & 63) == 0)
        atomicAdd(dst, v);
}

// ---------------------------------------------------------------------------
// Chamfer: for each (b,s,direction), each block handles QPB query points and
// scans the full 2048-point database staged in LDS.
// d^2(p,g) = |p|^2 - 2*(p.g - |g|^2/2); min_j d = sqrt(min_j d^2).
// grid.x = B*S*2*CHUNKS = 640
// ---------------------------------------------------------------------------
__global__ __launch_bounds__(256) void chamfer_kernel(
        const float* __restrict__ pred, const float* __restrict__ tgt,
        float* __restrict__ acc) {
    __shared__ float4 db[N];  // 32 KB: (x, y, z, 0.5*|g|^2)

    const int bid   = blockIdx.x;
    const int chunk = bid & (CHUNKS - 1);
    const int dir   = (bid >> 3) & 1;
    const int bs    = bid >> 4;               // 0..39  (b*S + s)

    const float* qbase = (dir == 0 ? pred : tgt) + (size_t)bs * N * 3;
    const float* dbase = (dir == 0 ? tgt : pred) + (size_t)bs * N * 3;

    // stage database into LDS
    for (int k = threadIdx.x; k < N; k += 256) {
        float x = dbase[3 * k + 0];
        float y = dbase[3 * k + 1];
        float z = dbase[3 * k + 2];
        db[k] = make_float4(x, y, z, 0.5f * (x * x + y * y + z * z));
    }
    __syncthreads();

    const int q = chunk * QPB + threadIdx.x;
    const float px = qbase[3 * q + 0];
    const float py = qbase[3 * q + 1];
    const float pz = qbase[3 * q + 2];
    const float pn = px * px + py * py + pz * pz;

    // maximize score = p.g - |g|^2/2  ->  min d^2 = |p|^2 - 2*max(score)
    float m0 = -1e30f, m1 = -1e30f, m2 = -1e30f, m3 = -1e30f;
    #pragma unroll 2
    for (int j = 0; j < N; j += 4) {
        float4 g0 = db[j + 0];
        float4 g1 = db[j + 1];
        float4 g2 = db[j + 2];
        float4 g3 = db[j + 3];
        m0 = fmaxf(m0, fmaf(px, g0.x, fmaf(py, g0.y, fmaf(pz, g0.z, -g0.w))));
        m1 = fmaxf(m1, fmaf(px, g1.x, fmaf(py, g1.y, fmaf(pz, g1.z, -g1.w))));
        m2 = fmaxf(m2, fmaf(px, g2.x, fmaf(py, g2.y, fmaf(pz, g2.z, -g2.w))));
        m3 = fmaxf(m3, fmaf(px, g3.x, fmaf(py, g3.y, fmaf(pz, g3.z, -g3.w))));
    }
    const float ms = fmaxf(fmaxf(m0, m1), fmaxf(m2, m3));
    const float d2 = fmaxf(pn - 2.0f * ms, 0.0f);
    const float dmin = sqrtf(d2);

    wave_reduce_atomic(dmin, acc + 0);
}

// ---------------------------------------------------------------------------
// KL divergence term sum over B*S*D elements
// ---------------------------------------------------------------------------
__global__ __launch_bounds__(256) void kl_kernel(
        const float* __restrict__ prior_mean, const float* __restrict__ prior_lv,
        const float* __restrict__ post_mean,  const float* __restrict__ post_lv,
        float* __restrict__ acc) {
    const int i = blockIdx.x * blockDim.x + threadIdx.x;
    float v = 0.0f;
    if (i < B * S * D) {
        float a  = prior_lv[i];
        float bb = post_lv[i];
        float dm = post_mean[i] - prior_mean[i];
        v = a - bb + (expf(bb) + dm * dm) * expf(-a) - 1.0f;
    }
    wave_reduce_atomic(v, acc + 1);
}

// ---------------------------------------------------------------------------
// Temporal smoothness: sum of ||pred[:,s+1]-pred[:,s]|| over B*(S-1)*N
// ---------------------------------------------------------------------------
__global__ __launch_bounds__(256) void temporal_kernel(
        const float* __restrict__ pred, float* __restrict__ acc) {
    constexpr int TOT = B * (S - 1) * N;
    const int i = blockIdx.x * blockDim.x + threadIdx.x;
    float v = 0.0f;
    if (i < TOT) {
        const int b = i / ((S - 1) * N);
        const int r = i % ((S - 1) * N);
        const int s = r / N;
        const int n = r % N;
        const float* p0 = pred + (size_t)(((b * S + s) * N + n)) * 3;
        const float* p1 = p0 + (size_t)N * 3;
        float dx = p1[0] - p0[0];
        float dy = p1[1] - p0[1];
        float dz = p1[2] - p0[2];
        v = sqrtf(dx * dx + dy * dy + dz * dz);
    }
    wave_reduce_atomic(v, acc + 2);
}

// ---------------------------------------------------------------------------
// Finalize: combine accumulators into the 5 outputs
// ---------------------------------------------------------------------------
__global__ void finalize_kernel(const float* __restrict__ acc, float* __restrict__ out) {
    if (threadIdx.x == 0 && blockIdx.x == 0) {
        float recon    = acc[0] / (float)(B * S * N);
        float kl       = 0.5f * acc[1] / (float)(B * S);
        float temporal = acc[2] / (float)(B * (S - 1) * N);
        out[0] = recon + kl + 0.1f * temporal;  // RECON_W=1, KL_W=1, TEMP_W=0.1, unc=0
        out[1] = recon;
        out[2] = kl;
        out[3] = temporal;
        out[4] = 0.0f;
    }
}

extern "C" void kernel_launch(void* const* d_in, const int* in_sizes, int n_in,
                              void* d_out, int out_size, void* d_ws, size_t ws_size,
                              hipStream_t stream) {
    const float* pred = (const float*)d_in[0];
    const float* tgt  = (const float*)d_in[1];
    const float* pm   = (const float*)d_in[2];
    const float* plv  = (const float*)d_in[3];
    const float* qm   = (const float*)d_in[4];
    const float* qlv  = (const float*)d_in[5];
    float* out = (float*)d_out;
    float* acc = (float*)d_ws;

    hipMemsetAsync(acc, 0, 3 * sizeof(float), stream);

    chamfer_kernel<<<B * S * 2 * CHUNKS, 256, 0, stream>>>(pred, tgt, acc);
    kl_kernel<<<(B * S * D + 255) / 256, 256, 0, stream>>>(pm, plv, qm, qlv, acc);
    temporal_kernel<<<(B * (S - 1) * N + 255) / 256, 256, 0, stream>>>(pred, acc);
    finalize_kernel<<<1, 64, 0, stream>>>(acc, out);
}

// Round 2
// 111.880 us; speedup vs baseline: 1.3400x; 1.3400x over previous
//
#include <hip/hip_runtime.h>
#include <hip/hip_bf16.h>
#include <math.h>

// Problem constants (from reference setup_inputs)
constexpr int B = 4, S = 10, N = 2048, D = 128;

constexpr int KS      = 8;            // database slices per (b,s,dir)
constexpr int SLICE   = N / KS;       // 256 db points per block
constexpr int QPT     = 8;            // queries per thread (all N queries per block)
constexpr int THREADS = 256;
constexpr int CHAM_BLOCKS = B * S * 2 * KS;   // 640
constexpr int TOTQ    = B * S * 2 * N;        // 163840 (query, dir) pairs
constexpr int TEMP_ELEMS = B * (S - 1) * N;   // 73728
constexpr int TEMP_BLOCKS = 16;
constexpr int TEMP_PER_BLOCK = TEMP_ELEMS / TEMP_BLOCKS;  // 4608 = 18*256
constexpr int KL_ELEMS = B * S * D;           // 5120 = 20*256

// ws layout (floats):
//   [0 .. KS*TOTQ)                 partial d^2 per (slice, query)
//   [KS*TOTQ .. +CHAM_BLOCKS)     per-block chamfer distance sums (K2)
//   then TEMP_BLOCKS temporal partials, then 1 kl partial
constexpr size_t WS_PARTIAL = 0;
constexpr size_t WS_CHSUM   = (size_t)KS * TOTQ;
constexpr size_t WS_TPART   = WS_CHSUM + CHAM_BLOCKS;
constexpr size_t WS_KL      = WS_TPART + TEMP_BLOCKS;

typedef float v2f __attribute__((ext_vector_type(2)));

__device__ __forceinline__ v2f pk_fma(v2f a, v2f b, v2f c) {
    v2f d;
    asm("v_pk_fma_f32 %0, %1, %2, %3" : "=v"(d) : "v"(a), "v"(b), "v"(c));
    return d;
}

// valid result on thread 0 only
__device__ __forceinline__ float block_sum(float v, float* red) {
    #pragma unroll
    for (int off = 32; off > 0; off >>= 1)
        v += __shfl_down(v, off, 64);
    const int wid = threadIdx.x >> 6;
    if ((threadIdx.x & 63) == 0) red[wid] = v;
    __syncthreads();
    return red[0] + red[1] + red[2] + red[3];
}

// ---------------------------------------------------------------------------
// K1: blocks [0,640): chamfer partials; [640,656): temporal; 656: kl
// ---------------------------------------------------------------------------
__global__ __launch_bounds__(256) void k1_kernel(
        const float* __restrict__ pred, const float* __restrict__ tgt,
        const float* __restrict__ prior_mean, const float* __restrict__ prior_lv,
        const float* __restrict__ post_mean,  const float* __restrict__ post_lv,
        float* __restrict__ ws) {
    __shared__ float4 db[SLICE];   // pair-interleaved: [2p]={x0,x1,y0,y1} [2p+1]={z0,z1,m0,m1}
    __shared__ float red[4];

    const int bid = blockIdx.x;
    const int tid = threadIdx.x;

    if (bid < CHAM_BLOCKS) {
        const int ks  = bid & (KS - 1);
        const int dir = (bid >> 3) & 1;
        const int bs  = bid >> 4;                 // b*S + s
        const float* qb  = (dir ? tgt : pred) + (size_t)bs * N * 3;  // queries
        const float* dbp = (dir ? pred : tgt) + (size_t)bs * N * 3;  // database

        // stage 256 db points, pair-interleaved, m = -0.5*|g|^2
        if (tid < SLICE / 2) {
            const int p0 = ks * SLICE + 2 * tid;
            const float x0 = dbp[3 * p0 + 0], y0 = dbp[3 * p0 + 1], z0 = dbp[3 * p0 + 2];
            const float x1 = dbp[3 * p0 + 3], y1 = dbp[3 * p0 + 4], z1 = dbp[3 * p0 + 5];
            db[2 * tid + 0] = make_float4(x0, x1, y0, y1);
            db[2 * tid + 1] = make_float4(z0, z1,
                                          -0.5f * (x0 * x0 + y0 * y0 + z0 * z0),
                                          -0.5f * (x1 * x1 + y1 * y1 + z1 * z1));
        }

        // load 8 queries into registers (splatted for packed fma)
        v2f px2[QPT], py2[QPT], pz2[QPT];
        float pn[QPT], acc[QPT];
        #pragma unroll
        for (int i = 0; i < QPT; ++i) {
            const int q = tid + THREADS * i;
            const float x = qb[3 * q + 0], y = qb[3 * q + 1], z = qb[3 * q + 2];
            px2[i] = (v2f){x, x};
            py2[i] = (v2f){y, y};
            pz2[i] = (v2f){z, z};
            pn[i]  = x * x + y * y + z * z;
            acc[i] = -1e30f;
        }
        __syncthreads();

        // max over slice of score = p.g - 0.5|g|^2 (2 db points per packed op)
        #pragma unroll 2
        for (int p = 0; p < SLICE / 2; ++p) {
            const float4 Axy = db[2 * p + 0];
            const float4 Bzm = db[2 * p + 1];
            const v2f x01 = (v2f){Axy.x, Axy.y};
            const v2f y01 = (v2f){Axy.z, Axy.w};
            const v2f z01 = (v2f){Bzm.x, Bzm.y};
            const v2f m01 = (v2f){Bzm.z, Bzm.w};
            #pragma unroll
            for (int i = 0; i < QPT; ++i) {
                v2f t = pk_fma(pz2[i], z01, m01);
                t = pk_fma(py2[i], y01, t);
                t = pk_fma(px2[i], x01, t);
                acc[i] = fmaxf(acc[i], fmaxf(t.x, t.y));   // v_max3_f32
            }
        }

        // partial d^2 for this slice
        float* part = ws + WS_PARTIAL + (size_t)ks * TOTQ + (size_t)(bs * 2 + dir) * N;
        #pragma unroll
        for (int i = 0; i < QPT; ++i)
            part[tid + THREADS * i] = pn[i] - 2.0f * acc[i];
    } else if (bid < CHAM_BLOCKS + TEMP_BLOCKS) {
        // temporal: sum ||pred[:,s+1]-pred[:,s]||
        const int tb = bid - CHAM_BLOCKS;
        float s = 0.0f;
        for (int it = 0; it < TEMP_PER_BLOCK / THREADS; ++it) {
            const int i = tb * TEMP_PER_BLOCK + it * THREADS + tid;
            const int b = i / ((S - 1) * N);
            const int r = i % ((S - 1) * N);
            const float* p0 = pred + (size_t)(b * S * N + r) * 3;
            const float* p1 = p0 + (size_t)N * 3;
            const float dx = p1[0] - p0[0];
            const float dy = p1[1] - p0[1];
            const float dz = p1[2] - p0[2];
            s += sqrtf(dx * dx + dy * dy + dz * dz);
        }
        const float tot = block_sum(s, red);
        if (tid == 0) ws[WS_TPART + tb] = tot;
    } else {
        // kl term sum
        float s = 0.0f;
        for (int it = 0; it < KL_ELEMS / THREADS; ++it) {
            const int i = it * THREADS + tid;
            const float a  = prior_lv[i];
            const float bb = post_lv[i];
            const float dm = post_mean[i] - prior_mean[i];
            s += a - bb + (expf(bb) + dm * dm) * expf(-a) - 1.0f;
        }
        const float tot = block_sum(s, red);
        if (tid == 0) ws[WS_KL] = tot;
    }
}

// ---------------------------------------------------------------------------
// K2: per query min over KS slices, sqrt, per-block sum (640 blocks x 256)
// ---------------------------------------------------------------------------
__global__ __launch_bounds__(256) void k2_kernel(float* __restrict__ ws) {
    __shared__ float red[4];
    const int u = blockIdx.x * THREADS + threadIdx.x;   // < TOTQ
    const float* part = ws + WS_PARTIAL;
    float d2 = part[u];
    #pragma unroll
    for (int k = 1; k < KS; ++k)
        d2 = fminf(d2, part[(size_t)k * TOTQ + u]);
    const float d = sqrtf(fmaxf(d2, 0.0f));
    const float tot = block_sum(d, red);
    if (threadIdx.x == 0) ws[WS_CHSUM + blockIdx.x] = tot;
}

// ---------------------------------------------------------------------------
// K3: final combine
// ---------------------------------------------------------------------------
__global__ __launch_bounds__(256) void k3_kernel(const float* __restrict__ ws,
                                                 float* __restrict__ out) {
    __shared__ float red[4];
    float s = 0.0f;
    for (int i = threadIdx.x; i < CHAM_BLOCKS; i += THREADS)
        s += ws[WS_CHSUM + i];
    const float tot = block_sum(s, red);
    if (threadIdx.x == 0) {
        float tsum = 0.0f;
        for (int i = 0; i < TEMP_BLOCKS; ++i) tsum += ws[WS_TPART + i];
        const float recon    = tot / (float)(B * S * N);
        const float kl       = 0.5f * ws[WS_KL] / (float)(B * S);
        const float temporal = tsum / (float)TEMP_ELEMS;
        out[0] = recon + kl + 0.1f * temporal;
        out[1] = recon;
        out[2] = kl;
        out[3] = temporal;
        out[4] = 0.0f;
    }
}

extern "C" void kernel_launch(void* const* d_in, const int* in_sizes, int n_in,
                              void* d_out, int out_size, void* d_ws, size_t ws_size,
                              hipStream_t stream) {
    const float* pred = (const float*)d_in[0];
    const float* tgt  = (const float*)d_in[1];
    const float* pm   = (const float*)d_in[2];
    const float* plv  = (const float*)d_in[3];
    const float* qm   = (const float*)d_in[4];
    const float* qlv  = (const float*)d_in[5];
    float* out = (float*)d_out;
    float* ws  = (float*)d_ws;

    k1_kernel<<<CHAM_BLOCKS + TEMP_BLOCKS + 1, THREADS, 0, stream>>>(
        pred, tgt, pm, plv, qm, qlv, ws);
    k2_kernel<<<TOTQ / THREADS, THREADS, 0, stream>>>(ws);
    k3_kernel<<<1, THREADS, 0, stream>>>(ws, out);
}